// Round 5
// baseline (1350.680 us; speedup 1.0000x reference)
//
#include <hip/hip_runtime.h>
#include <math.h>

#define NN 50000
#define NE 800000
#define IND 256
#define HD 128
#define NH 4
#define NC 32
#define RELN 100
#define RD 16
#define EHD 32

typedef unsigned int uint;

__device__ inline uint pack_bf16(float a, float b) {
    uint ua = __float_as_uint(a), ub = __float_as_uint(b);
    ua += 0x7fffu + ((ua >> 16) & 1u);
    ub += 0x7fffu + ((ub >> 16) & 1u);
    return (ua >> 16) | (ub & 0xffff0000u);
}

// ---------------- degree count ----------------
__global__ __launch_bounds__(256) void count_kernel(
    const int* __restrict__ dst, int* __restrict__ counts)
{
    int e = blockIdx.x * 256 + threadIdx.x;
    if (e < NE) atomicAdd(&counts[dst[e]], 1);
}

// ---------------- exclusive scan: single block, one ladder ----------------
__global__ __launch_bounds__(1024) void scan_kernel(
    const int* __restrict__ counts, int* __restrict__ row_ptr,
    int* __restrict__ cursor, int n)
{
    __shared__ int wsum[16];
    int tid = threadIdx.x;
    int C = (n + 1023) >> 10;           // 49
    int lo = tid * C, hi = min(lo + C, n);
    int s = 0;
    for (int i = lo; i < hi; i++) s += counts[i];
    int lane = tid & 63;
    int incl = s;
#pragma unroll
    for (int off = 1; off < 64; off <<= 1) {
        int v = __shfl_up(incl, off);
        if (lane >= off) incl += v;
    }
    if (lane == 63) wsum[tid >> 6] = incl;
    __syncthreads();
    if (tid < 16) {
        int v = wsum[tid];
        int inc2 = v;
#pragma unroll
        for (int off = 1; off < 16; off <<= 1) {
            int u = __shfl_up(inc2, off);
            if (tid >= off) inc2 += u;
        }
        wsum[tid] = inc2 - v;           // exclusive wave prefix
    }
    __syncthreads();
    int run = wsum[tid >> 6] + (incl - s);
    for (int i = lo; i < hi; i++) {
        row_ptr[i] = run; cursor[i] = run; run += counts[i];
    }
    if (tid == 1023) row_ptr[n] = run;
}

// ------- edge feature MLPs + CSR placement (fused fill), edge order -------
__global__ __launch_bounds__(256) void edge_feat_fill_kernel(
    const float* __restrict__ eattr, const int* __restrict__ src,
    const int* __restrict__ dst, int* __restrict__ cursor,
    const float* __restrict__ dW1, const float* __restrict__ db1,
    const float* __restrict__ dW2, const float* __restrict__ db2,
    const float* __restrict__ cW1, const float* __restrict__ cb1,
    const float* __restrict__ cW2, const float* __restrict__ cb2,
    const float* __restrict__ rel_emb,
    const float* __restrict__ fW1, const float* __restrict__ fb1,
    const float* __restrict__ fg,  const float* __restrict__ fbl,
    const float* __restrict__ fW2, const float* __restrict__ fb2,
    float* __restrict__ efeat_c, int* __restrict__ src_c,
    float* __restrict__ l2dw_c)
{
    int e = blockIdx.x * 256 + threadIdx.x;
    if (e >= NE) return;
    float d  = eattr[(size_t)e * 3 + 0];
    float cx = eattr[(size_t)e * 3 + 1];
    int r = (int)eattr[(size_t)e * 3 + 2];
    r = min(max(r, 0), RELN - 1);
    int p = atomicAdd(&cursor[dst[e]], 1);     // CSR slot
    src_c[p] = src[e];
    l2dw_c[p] = __log2f(d);

    float df[RD], cf[RD];
#pragma unroll
    for (int k = 0; k < RD; k++) { df[k] = db2[k]; cf[k] = cb2[k]; }
    for (int j = 0; j < EHD; j++) {
        float h1 = fmaxf(d  * dW1[j] + db1[j], 0.f);
        float h2 = fmaxf(cx * cW1[j] + cb1[j], 0.f);
#pragma unroll
        for (int k = 0; k < RD; k++) {
            df[k] += h1 * dW2[j * RD + k];
            cf[k] += h2 * cW2[j * RD + k];
        }
    }
    float hh[2 * RD];
#pragma unroll
    for (int m = 0; m < 2 * RD; m++) hh[m] = fb1[m];
    for (int k = 0; k < RD; k++) {
        float a = df[k], b = cf[k], c = rel_emb[r * RD + k];
#pragma unroll
        for (int m = 0; m < 2 * RD; m++) {
            hh[m] += a * fW1[k * (2 * RD) + m]
                   + b * fW1[(RD + k) * (2 * RD) + m]
                   + c * fW1[(2 * RD + k) * (2 * RD) + m];
        }
    }
    float s = 0.f;
#pragma unroll
    for (int m = 0; m < 2 * RD; m++) s += hh[m];
    float mean = s * (1.f / (2 * RD));
    float s2 = 0.f;
#pragma unroll
    for (int m = 0; m < 2 * RD; m++) { float dd = hh[m] - mean; s2 += dd * dd; }
    float rs = rsqrtf(s2 * (1.f / (2 * RD)) + 1e-5f);
#pragma unroll
    for (int m = 0; m < 2 * RD; m++)
        hh[m] = fmaxf((hh[m] - mean) * rs * fg[m] + fbl[m], 0.f);

    float ef[RD];
#pragma unroll
    for (int k = 0; k < RD; k++) ef[k] = fb2[k];
    for (int m = 0; m < 2 * RD; m++) {
        float hv = hh[m];
#pragma unroll
        for (int k = 0; k < RD; k++) ef[k] += hv * fW2[m * RD + k];
    }
    float4* ep = (float4*)(efeat_c + (size_t)p * RD);
#pragma unroll
    for (int q = 0; q < 4; q++)
        ep[q] = make_float4(ef[4 * q], ef[4 * q + 1], ef[4 * q + 2], ef[4 * q + 3]);
}

// ---------------- input LN + projection (8 nodes / block) ----------------
__global__ __launch_bounds__(256) void ln_proj_kernel(
    const float* __restrict__ x, const float* __restrict__ g, const float* __restrict__ b,
    const float* __restrict__ W, const float* __restrict__ pb, float* __restrict__ x0)
{
    __shared__ float xr[8][IND];
    __shared__ float mv[8][2];
    int nb = blockIdx.x * 8;
    int tid = threadIdx.x;
    const float4* xv = (const float4*)(x + (size_t)nb * IND);
    float4* xl = (float4*)&xr[0][0];
    xl[tid] = xv[tid];
    xl[tid + 256] = xv[tid + 256];
    __syncthreads();
    int node = tid >> 5, lane = tid & 31;
    float s1 = 0.f, s2 = 0.f;
#pragma unroll
    for (int j = 0; j < 8; j++) { float v = xr[node][lane + 32 * j]; s1 += v; s2 += v * v; }
#pragma unroll
    for (int off = 16; off >= 1; off >>= 1) { s1 += __shfl_xor(s1, off); s2 += __shfl_xor(s2, off); }
    if (lane == 0) {
        float mean = s1 * (1.f / IND);
        mv[node][0] = mean;
        mv[node][1] = rsqrtf(s2 * (1.f / IND) - mean * mean + 1e-5f);
    }
    __syncthreads();
#pragma unroll
    for (int j = 0; j < 8; j++) {
        int k = lane + 32 * j;
        xr[node][k] = (xr[node][k] - mv[node][0]) * mv[node][1] * g[k] + b[k];
    }
    __syncthreads();
    int col = tid & 127, r0 = (tid >> 7) * 4;
    float acc[4] = {0.f, 0.f, 0.f, 0.f};
    for (int k = 0; k < IND; k += 4) {
        float4 x4[4];
#pragma unroll
        for (int r = 0; r < 4; r++) x4[r] = *(const float4*)&xr[r0 + r][k];
        float w0 = W[(k + 0) * HD + col];
        float w1 = W[(k + 1) * HD + col];
        float w2 = W[(k + 2) * HD + col];
        float w3 = W[(k + 3) * HD + col];
#pragma unroll
        for (int r = 0; r < 4; r++)
            acc[r] += x4[r].x * w0 + x4[r].y * w1 + x4[r].z * w2 + x4[r].w * w3;
    }
    float pbv = pb[col];
#pragma unroll
    for (int r = 0; r < 4; r++)
        x0[(size_t)(nb + r0 + r) * HD + col] = acc[r] + pbv;
}

// ------- xs = bf16-packed x@Wsrc ; xd = f32 x@Wdst -------
__global__ __launch_bounds__(256) void gemm_sd_kernel(
    const float* __restrict__ x, const float* __restrict__ Ws, const float* __restrict__ Wd,
    uint* __restrict__ xs_p, float2* __restrict__ xd2)
{
    __shared__ float xt[32][HD];
    int nb = blockIdx.x * 32;
    int tid = threadIdx.x;
    const float4* xv = (const float4*)(x + (size_t)nb * HD);
    float4* xl = (float4*)&xt[0][0];
    int validf4 = (NN - nb >= 32) ? 1024 : (NN - nb) * 32;
    for (int idx = tid; idx < 1024; idx += 256) {
        float4 v = {0.f, 0.f, 0.f, 0.f};
        if (idx < validf4) v = xv[idx];
        xl[idx] = v;
    }
    __syncthreads();
    int ct = blockIdx.y;                 // 0: xs(bf16)   1: xd(f32)
    const float* W = ct ? Wd : Ws;
    const float2* W2v = (const float2*)W;
    int cp = tid & 63;                   // column pair: cols 2cp, 2cp+1
    int r0 = (tid >> 6) * 8;
    float a0[8] = {0.f}, a1[8] = {0.f};
    for (int k = 0; k < HD; k += 4) {
        float4 x4[8];
#pragma unroll
        for (int r = 0; r < 8; r++) x4[r] = *(const float4*)&xt[r0 + r][k];
        float2 w0 = W2v[(k + 0) * 64 + cp];
        float2 w1 = W2v[(k + 1) * 64 + cp];
        float2 w2 = W2v[(k + 2) * 64 + cp];
        float2 w3 = W2v[(k + 3) * 64 + cp];
#pragma unroll
        for (int r = 0; r < 8; r++) {
            a0[r] += x4[r].x * w0.x + x4[r].y * w1.x + x4[r].z * w2.x + x4[r].w * w3.x;
            a1[r] += x4[r].x * w0.y + x4[r].y * w1.y + x4[r].z * w2.y + x4[r].w * w3.y;
        }
    }
    if (ct == 0) {
#pragma unroll
        for (int r = 0; r < 8; r++) {
            int n = nb + r0 + r;
            if (n < NN) xs_p[(size_t)n * 64 + cp] = pack_bf16(a0[r], a1[r]);
        }
    } else {
#pragma unroll
        for (int r = 0; r < 8; r++) {
            int n = nb + r0 + r;
            if (n < NN) xd2[(size_t)n * 64 + cp] = make_float2(a0[r], a1[r]);
        }
    }
}

// ------- per-layer attention aggregate + LN + ELU + residual -------
// one node per 128-thread block; TWO waves split the edge list; LDS combine
__global__ __launch_bounds__(128) void aggregate_kernel(
    const uint* __restrict__ xs_p, const float2* __restrict__ xd2,
    const float* __restrict__ efeat_c, const float* __restrict__ l2dw_c,
    const int* __restrict__ src_c, const int* __restrict__ row_ptr,
    const float* __restrict__ Wedge_i, const float2* __restrict__ att2,
    const float* __restrict__ sscale_i, const float2* __restrict__ ng2,
    const float2* __restrict__ nb2, float2* __restrict__ xio2, int apply_dist)
{
    __shared__ float cs[3][64];
    int l  = threadIdx.x & 63;
    int wv = threadIdx.x >> 6;          // 0 or 1
    int node = blockIdx.x;

    const float2* w2 = (const float2*)Wedge_i;
    float2 wcol[RD];
#pragma unroll
    for (int k = 0; k < RD; k++) wcol[k] = w2[k * 64 + l];
    float2 attv = att2[l];
    float2 xdv  = xd2[(size_t)node * 64 + l];
    float2 xres = xio2[(size_t)node * 64 + l];
    float sc = sscale_i[l >> 4];

    int e0 = row_ptr[node], e1 = row_ptr[node + 1];
    float esum = 0.f;
    float2 macc = {0.f, 0.f};

    // wave wv takes 8-edge batches at e0+8*wv, stride 16
    for (int b = e0 + wv * 8; b < e1; b += 16) {
        int pp[8], ss[8];
        float lg[8];
        uint xw[8];
#pragma unroll
        for (int j = 0; j < 8; j++) {
            pp[j] = min(b + j, e1 - 1);
            ss[j] = src_c[pp[j]];
            lg[j] = l2dw_c[pp[j]];
        }
#pragma unroll
        for (int j = 0; j < 8; j++) xw[j] = xs_p[(size_t)ss[j] * 64 + l];
#pragma unroll
        for (int j = 0; j < 8; j++) {
            const float4* ep = (const float4*)(efeat_c + (size_t)pp[j] * RD);
            float4 f0 = ep[0], f1 = ep[1], f2 = ep[2], f3 = ep[3];
            float ev[RD] = { f0.x, f0.y, f0.z, f0.w, f1.x, f1.y, f1.z, f1.w,
                             f2.x, f2.y, f2.z, f2.w, f3.x, f3.y, f3.z, f3.w };
            float efx = 0.f, efy = 0.f;
#pragma unroll
            for (int k = 0; k < RD; k++) { efx += ev[k] * wcol[k].x; efy += ev[k] * wcol[k].y; }
            float xvx = __uint_as_float(xw[j] << 16);
            float xvy = __uint_as_float(xw[j] & 0xffff0000u);
            float zx = xvx + xdv.x + efx;
            float zy = xvy + xdv.y + efy;
            float tx = 1.f - 2.f * __builtin_amdgcn_rcpf(__expf(2.f * zx) + 1.f);
            float ty = 1.f - 2.f * __builtin_amdgcn_rcpf(__expf(2.f * zy) + 1.f);
            float a = tx * attv.x + ty * attv.y;
#pragma unroll
            for (int off = 8; off >= 1; off >>= 1) a += __shfl_xor(a, off);
            if (apply_dist) a *= exp2f(lg[j] * sc);
            float ea = __expf(a);
            ea = (b + j < e1) ? ea : 0.f;
            esum += ea;
            macc.x += xvx * ea;
            macc.y += xvy * ea;
        }
    }
    if (wv == 1) { cs[0][l] = esum; cs[1][l] = macc.x; cs[2][l] = macc.y; }
    __syncthreads();
    if (wv == 1) return;
    esum   += cs[0][l];
    macc.x += cs[1][l];
    macc.y += cs[2][l];

    float inv = __builtin_amdgcn_rcpf(esum + 1e-8f);
    float2 outv = { macc.x * inv, macc.y * inv };

    float s1 = outv.x + outv.y;
    float s2 = outv.x * outv.x + outv.y * outv.y;
#pragma unroll
    for (int off = 32; off >= 1; off >>= 1) { s1 += __shfl_xor(s1, off); s2 += __shfl_xor(s2, off); }
    float mean = s1 * (1.f / HD);
    float var = s2 * (1.f / HD) - mean * mean;
    float rstd = rsqrtf(var + 1e-5f);
    float2 g = ng2[l], bb = nb2[l];
    float yx = (outv.x - mean) * rstd * g.x + bb.x;
    float yy = (outv.y - mean) * rstd * g.y + bb.y;
    float ex = (yx > 0.f) ? yx : expm1f(yx);
    float ey = (yy > 0.f) ? yy : expm1f(yy);
    float2 res;
    res.x = ex + xres.x;
    res.y = ey + xres.y;
    xio2[(size_t)node * 64 + l] = res;
}

extern "C" void kernel_launch(void* const* d_in, const int* in_sizes, int n_in,
                              void* d_out, int out_size, void* d_ws, size_t ws_size,
                              hipStream_t stream)
{
    const float* x_in   = (const float*)d_in[0];
    const int*   eidx   = (const int*)  d_in[1];
    const float* eattr  = (const float*)d_in[2];
    const float* in_g   = (const float*)d_in[3];
    const float* in_b   = (const float*)d_in[4];
    const float* proj_W = (const float*)d_in[5];
    const float* proj_b = (const float*)d_in[6];
    const float* dW1    = (const float*)d_in[7];
    const float* db1    = (const float*)d_in[8];
    const float* dW2    = (const float*)d_in[9];
    const float* db2    = (const float*)d_in[10];
    const float* cW1    = (const float*)d_in[11];
    const float* cb1    = (const float*)d_in[12];
    const float* cW2    = (const float*)d_in[13];
    const float* cb2    = (const float*)d_in[14];
    const float* rel_emb= (const float*)d_in[15];
    const float* fW1    = (const float*)d_in[16];
    const float* fb1    = (const float*)d_in[17];
    const float* fg     = (const float*)d_in[18];
    const float* fbl    = (const float*)d_in[19];
    const float* fW2    = (const float*)d_in[20];
    const float* fb2    = (const float*)d_in[21];
    const float* Wsrc   = (const float*)d_in[22];
    const float* Wdst   = (const float*)d_in[23];
    const float* Wedge  = (const float*)d_in[24];
    const float* att    = (const float*)d_in[25];
    const float* sscale = (const float*)d_in[26];
    const float* ng     = (const float*)d_in[27];
    const float* nb     = (const float*)d_in[28];

    const int* src = eidx;
    const int* dst = eidx + NE;

    char* p = (char*)d_ws;
    auto alloc = [&](size_t bytes) -> void* {
        void* r = p;
        p += (bytes + 255) & ~(size_t)255;
        return r;
    };
    uint*  xs_p    = (uint*) alloc((size_t)NN * 64 * 4);      // bf16-packed
    float* xd      = (float*)alloc((size_t)NN * HD * 4);
    float* efeat_c = (float*)alloc((size_t)NE * RD * 4);
    int*   counts  = (int*)  alloc((size_t)NN * 4);
    int*   row_ptr = (int*)  alloc(((size_t)NN + 1) * 4);
    int*   cursor  = (int*)  alloc((size_t)NN * 4);
    int*   src_c   = (int*)  alloc((size_t)NE * 4);
    float* l2dw_c  = (float*)alloc((size_t)NE * 4);

    float* x_cur = (float*)d_out;

    hipMemsetAsync(counts, 0, (size_t)NN * 4, stream);
    hipLaunchKernelGGL(count_kernel, dim3(NE / 256), dim3(256), 0, stream, dst, counts);
    hipLaunchKernelGGL(scan_kernel, dim3(1), dim3(1024), 0, stream,
        counts, row_ptr, cursor, NN);
    hipLaunchKernelGGL(edge_feat_fill_kernel, dim3(NE / 256), dim3(256), 0, stream,
        eattr, src, dst, cursor, dW1, db1, dW2, db2, cW1, cb1, cW2, cb2, rel_emb,
        fW1, fb1, fg, fbl, fW2, fb2, efeat_c, src_c, l2dw_c);
    hipLaunchKernelGGL(ln_proj_kernel, dim3(NN / 8), dim3(256), 0, stream,
        x_in, in_g, in_b, proj_W, proj_b, x_cur);

    for (int i = 0; i < 3; i++) {
        hipLaunchKernelGGL(gemm_sd_kernel, dim3((NN + 31) / 32, 2), dim3(256), 0, stream,
            x_cur, Wsrc + (size_t)i * HD * HD, Wdst + (size_t)i * HD * HD,
            xs_p, (float2*)xd);
        hipLaunchKernelGGL(aggregate_kernel, dim3(NN), dim3(128), 0, stream,
            xs_p, (const float2*)xd, efeat_c, l2dw_c, src_c, row_ptr,
            Wedge + (size_t)i * RD * HD, (const float2*)(att + (size_t)i * NH * NC),
            sscale + (size_t)i * NH,
            (const float2*)(ng + (size_t)i * HD), (const float2*)(nb + (size_t)i * HD),
            (float2*)x_cur, (i < 2) ? 1 : 0);
    }
}

// Round 6
// 1091.089 us; speedup vs baseline: 1.2379x; 1.2379x over previous
//
#include <hip/hip_runtime.h>
#include <math.h>

#define NN 50000
#define NE 800000
#define IND 256
#define HD 128
#define NH 4
#define NC 32
#define RELN 100
#define RD 16
#define EHD 32

typedef unsigned int uint;

__device__ inline uint pack_bf16(float a, float b) {
    uint ua = __float_as_uint(a), ub = __float_as_uint(b);
    ua += 0x7fffu + ((ua >> 16) & 1u);
    ub += 0x7fffu + ((ub >> 16) & 1u);
    return (ua >> 16) | (ub & 0xffff0000u);
}

// ---------------- degree count ----------------
__global__ __launch_bounds__(256) void count_kernel(
    const int* __restrict__ dst, int* __restrict__ counts)
{
    int e = blockIdx.x * 256 + threadIdx.x;
    if (e < NE) atomicAdd(&counts[dst[e]], 1);
}

// ---------------- exclusive scan: single block, one ladder ----------------
__global__ __launch_bounds__(1024) void scan_kernel(
    const int* __restrict__ counts, int* __restrict__ row_ptr,
    int* __restrict__ cursor, int n)
{
    __shared__ int wsum[16];
    int tid = threadIdx.x;
    int C = (n + 1023) >> 10;           // 49
    int lo = tid * C, hi = min(lo + C, n);
    int s = 0;
    for (int i = lo; i < hi; i++) s += counts[i];
    int lane = tid & 63;
    int incl = s;
#pragma unroll
    for (int off = 1; off < 64; off <<= 1) {
        int v = __shfl_up(incl, off);
        if (lane >= off) incl += v;
    }
    if (lane == 63) wsum[tid >> 6] = incl;
    __syncthreads();
    if (tid < 16) {
        int v = wsum[tid];
        int inc2 = v;
#pragma unroll
        for (int off = 1; off < 16; off <<= 1) {
            int u = __shfl_up(inc2, off);
            if (tid >= off) inc2 += u;
        }
        wsum[tid] = inc2 - v;           // exclusive wave prefix
    }
    __syncthreads();
    int run = wsum[tid >> 6] + (incl - s);
    for (int i = lo; i < hi; i++) {
        row_ptr[i] = run; cursor[i] = run; run += counts[i];
    }
    if (tid == 1023) row_ptr[n] = run;
}

// ------- edge feature MLPs + CSR placement (fused fill), edge order -------
__global__ __launch_bounds__(256) void edge_feat_fill_kernel(
    const float* __restrict__ eattr, const int* __restrict__ src,
    const int* __restrict__ dst, int* __restrict__ cursor,
    const float* __restrict__ dW1, const float* __restrict__ db1,
    const float* __restrict__ dW2, const float* __restrict__ db2,
    const float* __restrict__ cW1, const float* __restrict__ cb1,
    const float* __restrict__ cW2, const float* __restrict__ cb2,
    const float* __restrict__ rel_emb,
    const float* __restrict__ fW1, const float* __restrict__ fb1,
    const float* __restrict__ fg,  const float* __restrict__ fbl,
    const float* __restrict__ fW2, const float* __restrict__ fb2,
    float* __restrict__ efeat_c, int2* __restrict__ meta_c)
{
    int e = blockIdx.x * 256 + threadIdx.x;
    if (e >= NE) return;
    float d  = eattr[(size_t)e * 3 + 0];
    float cx = eattr[(size_t)e * 3 + 1];
    int r = (int)eattr[(size_t)e * 3 + 2];
    r = min(max(r, 0), RELN - 1);
    int p = atomicAdd(&cursor[dst[e]], 1);     // CSR slot
    meta_c[p] = make_int2(src[e], __float_as_int(__log2f(d)));

    float df[RD], cf[RD];
#pragma unroll
    for (int k = 0; k < RD; k++) { df[k] = db2[k]; cf[k] = cb2[k]; }
    for (int j = 0; j < EHD; j++) {
        float h1 = fmaxf(d  * dW1[j] + db1[j], 0.f);
        float h2 = fmaxf(cx * cW1[j] + cb1[j], 0.f);
#pragma unroll
        for (int k = 0; k < RD; k++) {
            df[k] += h1 * dW2[j * RD + k];
            cf[k] += h2 * cW2[j * RD + k];
        }
    }
    float hh[2 * RD];
#pragma unroll
    for (int m = 0; m < 2 * RD; m++) hh[m] = fb1[m];
    for (int k = 0; k < RD; k++) {
        float a = df[k], b = cf[k], c = rel_emb[r * RD + k];
#pragma unroll
        for (int m = 0; m < 2 * RD; m++) {
            hh[m] += a * fW1[k * (2 * RD) + m]
                   + b * fW1[(RD + k) * (2 * RD) + m]
                   + c * fW1[(2 * RD + k) * (2 * RD) + m];
        }
    }
    float s = 0.f;
#pragma unroll
    for (int m = 0; m < 2 * RD; m++) s += hh[m];
    float mean = s * (1.f / (2 * RD));
    float s2 = 0.f;
#pragma unroll
    for (int m = 0; m < 2 * RD; m++) { float dd = hh[m] - mean; s2 += dd * dd; }
    float rs = rsqrtf(s2 * (1.f / (2 * RD)) + 1e-5f);
#pragma unroll
    for (int m = 0; m < 2 * RD; m++)
        hh[m] = fmaxf((hh[m] - mean) * rs * fg[m] + fbl[m], 0.f);

    float ef[RD];
#pragma unroll
    for (int k = 0; k < RD; k++) ef[k] = fb2[k];
    for (int m = 0; m < 2 * RD; m++) {
        float hv = hh[m];
#pragma unroll
        for (int k = 0; k < RD; k++) ef[k] += hv * fW2[m * RD + k];
    }
    float4* ep = (float4*)(efeat_c + (size_t)p * RD);
#pragma unroll
    for (int q = 0; q < 4; q++)
        ep[q] = make_float4(ef[4 * q], ef[4 * q + 1], ef[4 * q + 2], ef[4 * q + 3]);
}

// ---------------- input LN + projection (8 nodes / block) ----------------
__global__ __launch_bounds__(256) void ln_proj_kernel(
    const float* __restrict__ x, const float* __restrict__ g, const float* __restrict__ b,
    const float* __restrict__ W, const float* __restrict__ pb, float* __restrict__ x0)
{
    __shared__ float xr[8][IND];
    __shared__ float mv[8][2];
    int nb = blockIdx.x * 8;
    int tid = threadIdx.x;
    const float4* xv = (const float4*)(x + (size_t)nb * IND);
    float4* xl = (float4*)&xr[0][0];
    xl[tid] = xv[tid];
    xl[tid + 256] = xv[tid + 256];
    __syncthreads();
    int node = tid >> 5, lane = tid & 31;
    float s1 = 0.f, s2 = 0.f;
#pragma unroll
    for (int j = 0; j < 8; j++) { float v = xr[node][lane + 32 * j]; s1 += v; s2 += v * v; }
#pragma unroll
    for (int off = 16; off >= 1; off >>= 1) { s1 += __shfl_xor(s1, off); s2 += __shfl_xor(s2, off); }
    if (lane == 0) {
        float mean = s1 * (1.f / IND);
        mv[node][0] = mean;
        mv[node][1] = rsqrtf(s2 * (1.f / IND) - mean * mean + 1e-5f);
    }
    __syncthreads();
#pragma unroll
    for (int j = 0; j < 8; j++) {
        int k = lane + 32 * j;
        xr[node][k] = (xr[node][k] - mv[node][0]) * mv[node][1] * g[k] + b[k];
    }
    __syncthreads();
    int col = tid & 127, r0 = (tid >> 7) * 4;
    float acc[4] = {0.f, 0.f, 0.f, 0.f};
    for (int k = 0; k < IND; k += 4) {
        float4 x4[4];
#pragma unroll
        for (int r = 0; r < 4; r++) x4[r] = *(const float4*)&xr[r0 + r][k];
        float w0 = W[(k + 0) * HD + col];
        float w1 = W[(k + 1) * HD + col];
        float w2 = W[(k + 2) * HD + col];
        float w3 = W[(k + 3) * HD + col];
#pragma unroll
        for (int r = 0; r < 4; r++)
            acc[r] += x4[r].x * w0 + x4[r].y * w1 + x4[r].z * w2 + x4[r].w * w3;
    }
    float pbv = pb[col];
#pragma unroll
    for (int r = 0; r < 4; r++)
        x0[(size_t)(nb + r0 + r) * HD + col] = acc[r] + pbv;
}

// ------- xs = bf16-packed x@Wsrc ; xd = f32 x@Wdst -------
__global__ __launch_bounds__(256) void gemm_sd_kernel(
    const float* __restrict__ x, const float* __restrict__ Ws, const float* __restrict__ Wd,
    uint* __restrict__ xs_p, float2* __restrict__ xd2)
{
    __shared__ float xt[32][HD];
    int nb = blockIdx.x * 32;
    int tid = threadIdx.x;
    const float4* xv = (const float4*)(x + (size_t)nb * HD);
    float4* xl = (float4*)&xt[0][0];
    int validf4 = (NN - nb >= 32) ? 1024 : (NN - nb) * 32;
    for (int idx = tid; idx < 1024; idx += 256) {
        float4 v = {0.f, 0.f, 0.f, 0.f};
        if (idx < validf4) v = xv[idx];
        xl[idx] = v;
    }
    __syncthreads();
    int ct = blockIdx.y;                 // 0: xs(bf16)   1: xd(f32)
    const float* W = ct ? Wd : Ws;
    const float2* W2v = (const float2*)W;
    int cp = tid & 63;                   // column pair: cols 2cp, 2cp+1
    int r0 = (tid >> 6) * 8;
    float a0[8] = {0.f}, a1[8] = {0.f};
    for (int k = 0; k < HD; k += 4) {
        float4 x4[8];
#pragma unroll
        for (int r = 0; r < 8; r++) x4[r] = *(const float4*)&xt[r0 + r][k];
        float2 w0 = W2v[(k + 0) * 64 + cp];
        float2 w1 = W2v[(k + 1) * 64 + cp];
        float2 w2 = W2v[(k + 2) * 64 + cp];
        float2 w3 = W2v[(k + 3) * 64 + cp];
#pragma unroll
        for (int r = 0; r < 8; r++) {
            a0[r] += x4[r].x * w0.x + x4[r].y * w1.x + x4[r].z * w2.x + x4[r].w * w3.x;
            a1[r] += x4[r].x * w0.y + x4[r].y * w1.y + x4[r].z * w2.y + x4[r].w * w3.y;
        }
    }
    if (ct == 0) {
#pragma unroll
        for (int r = 0; r < 8; r++) {
            int n = nb + r0 + r;
            if (n < NN) xs_p[(size_t)n * 64 + cp] = pack_bf16(a0[r], a1[r]);
        }
    } else {
#pragma unroll
        for (int r = 0; r < 8; r++) {
            int n = nb + r0 + r;
            if (n < NN) xd2[(size_t)n * 64 + cp] = make_float2(a0[r], a1[r]);
        }
    }
}

// ------- per-layer attention aggregate + LN + ELU + residual -------
// wave = worker; each wave grid-strides over nodes; layer consts loaded once
__global__ __launch_bounds__(256) void aggregate_kernel(
    const uint* __restrict__ xs_p, const float2* __restrict__ xd2,
    const float* __restrict__ efeat_c, const int2* __restrict__ meta_c,
    const int* __restrict__ row_ptr,
    const float* __restrict__ Wedge_i, const float2* __restrict__ att2,
    const float* __restrict__ sscale_i, const float2* __restrict__ ng2,
    const float2* __restrict__ nb2, float2* __restrict__ xio2,
    int apply_dist, int nwaves)
{
    int l = threadIdx.x & 63;
    int wid = blockIdx.x * 4 + __builtin_amdgcn_readfirstlane(threadIdx.x >> 6);

    // -------- layer constants: loaded ONCE per wave --------
    const float2* w2 = (const float2*)Wedge_i;
    float2 wcol[RD];
#pragma unroll
    for (int k = 0; k < RD; k++) wcol[k] = w2[k * 64 + l];
    float2 attv = att2[l];
    float sc = sscale_i[l >> 4];
    float2 g = ng2[l], bb = nb2[l];

    for (int node = wid; node < NN; node += nwaves) {
        int e0 = row_ptr[node], e1 = row_ptr[node + 1];
        float2 xdv  = xd2[(size_t)node * 64 + l];
        float2 xres = xio2[(size_t)node * 64 + l];
        float esum = 0.f;
        float2 macc = {0.f, 0.f};

        for (int b = e0; b < e1; b += 4) {
            int pp[4];
            int2 mt[4];
            uint xw[4];
#pragma unroll
            for (int j = 0; j < 4; j++) {
                pp[j] = min(b + j, e1 - 1);
                mt[j] = meta_c[pp[j]];
            }
#pragma unroll
            for (int j = 0; j < 4; j++) xw[j] = xs_p[(size_t)mt[j].x * 64 + l];
#pragma unroll
            for (int j = 0; j < 4; j++) {
                const float4* ep = (const float4*)(efeat_c + (size_t)pp[j] * RD);
                float4 f0 = ep[0], f1 = ep[1], f2 = ep[2], f3 = ep[3];
                float ev[RD] = { f0.x, f0.y, f0.z, f0.w, f1.x, f1.y, f1.z, f1.w,
                                 f2.x, f2.y, f2.z, f2.w, f3.x, f3.y, f3.z, f3.w };
                float efx = 0.f, efy = 0.f;
#pragma unroll
                for (int k = 0; k < RD; k++) { efx += ev[k] * wcol[k].x; efy += ev[k] * wcol[k].y; }
                float xvx = __uint_as_float(xw[j] << 16);
                float xvy = __uint_as_float(xw[j] & 0xffff0000u);
                float zx = xvx + xdv.x + efx;
                float zy = xvy + xdv.y + efy;
                float tx = 1.f - 2.f * __builtin_amdgcn_rcpf(__expf(2.f * zx) + 1.f);
                float ty = 1.f - 2.f * __builtin_amdgcn_rcpf(__expf(2.f * zy) + 1.f);
                float a = tx * attv.x + ty * attv.y;
#pragma unroll
                for (int off = 8; off >= 1; off >>= 1) a += __shfl_xor(a, off);
                if (apply_dist) a *= exp2f(__int_as_float(mt[j].y) * sc);
                float ea = __expf(a);
                ea = (b + j < e1) ? ea : 0.f;
                esum += ea;
                macc.x += xvx * ea;
                macc.y += xvy * ea;
            }
        }
        float inv = __builtin_amdgcn_rcpf(esum + 1e-8f);
        float2 outv = { macc.x * inv, macc.y * inv };

        float s1 = outv.x + outv.y;
        float s2 = outv.x * outv.x + outv.y * outv.y;
#pragma unroll
        for (int off = 32; off >= 1; off >>= 1) { s1 += __shfl_xor(s1, off); s2 += __shfl_xor(s2, off); }
        float mean = s1 * (1.f / HD);
        float var = s2 * (1.f / HD) - mean * mean;
        float rstd = rsqrtf(var + 1e-5f);
        float yx = (outv.x - mean) * rstd * g.x + bb.x;
        float yy = (outv.y - mean) * rstd * g.y + bb.y;
        float ex = (yx > 0.f) ? yx : expm1f(yx);
        float ey = (yy > 0.f) ? yy : expm1f(yy);
        float2 res;
        res.x = ex + xres.x;
        res.y = ey + xres.y;
        xio2[(size_t)node * 64 + l] = res;
    }
}

extern "C" void kernel_launch(void* const* d_in, const int* in_sizes, int n_in,
                              void* d_out, int out_size, void* d_ws, size_t ws_size,
                              hipStream_t stream)
{
    const float* x_in   = (const float*)d_in[0];
    const int*   eidx   = (const int*)  d_in[1];
    const float* eattr  = (const float*)d_in[2];
    const float* in_g   = (const float*)d_in[3];
    const float* in_b   = (const float*)d_in[4];
    const float* proj_W = (const float*)d_in[5];
    const float* proj_b = (const float*)d_in[6];
    const float* dW1    = (const float*)d_in[7];
    const float* db1    = (const float*)d_in[8];
    const float* dW2    = (const float*)d_in[9];
    const float* db2    = (const float*)d_in[10];
    const float* cW1    = (const float*)d_in[11];
    const float* cb1    = (const float*)d_in[12];
    const float* cW2    = (const float*)d_in[13];
    const float* cb2    = (const float*)d_in[14];
    const float* rel_emb= (const float*)d_in[15];
    const float* fW1    = (const float*)d_in[16];
    const float* fb1    = (const float*)d_in[17];
    const float* fg     = (const float*)d_in[18];
    const float* fbl    = (const float*)d_in[19];
    const float* fW2    = (const float*)d_in[20];
    const float* fb2    = (const float*)d_in[21];
    const float* Wsrc   = (const float*)d_in[22];
    const float* Wdst   = (const float*)d_in[23];
    const float* Wedge  = (const float*)d_in[24];
    const float* att    = (const float*)d_in[25];
    const float* sscale = (const float*)d_in[26];
    const float* ng     = (const float*)d_in[27];
    const float* nb     = (const float*)d_in[28];

    const int* src = eidx;
    const int* dst = eidx + NE;

    char* p = (char*)d_ws;
    auto alloc = [&](size_t bytes) -> void* {
        void* r = p;
        p += (bytes + 255) & ~(size_t)255;
        return r;
    };
    uint*  xs_p    = (uint*) alloc((size_t)NN * 64 * 4);      // bf16-packed
    float* xd      = (float*)alloc((size_t)NN * HD * 4);
    float* efeat_c = (float*)alloc((size_t)NE * RD * 4);
    int*   counts  = (int*)  alloc((size_t)NN * 4);
    int*   row_ptr = (int*)  alloc(((size_t)NN + 1) * 4);
    int*   cursor  = (int*)  alloc((size_t)NN * 4);
    int2*  meta_c  = (int2*) alloc((size_t)NE * 8);

    float* x_cur = (float*)d_out;

    hipMemsetAsync(counts, 0, (size_t)NN * 4, stream);
    hipLaunchKernelGGL(count_kernel, dim3(NE / 256), dim3(256), 0, stream, dst, counts);
    hipLaunchKernelGGL(scan_kernel, dim3(1), dim3(1024), 0, stream,
        counts, row_ptr, cursor, NN);
    hipLaunchKernelGGL(edge_feat_fill_kernel, dim3(NE / 256), dim3(256), 0, stream,
        eattr, src, dst, cursor, dW1, db1, dW2, db2, cW1, cb1, cW2, cb2, rel_emb,
        fW1, fb1, fg, fbl, fW2, fb2, efeat_c, meta_c);
    hipLaunchKernelGGL(ln_proj_kernel, dim3(NN / 8), dim3(256), 0, stream,
        x_in, in_g, in_b, proj_W, proj_b, x_cur);

    const int AGG_BLOCKS = 2048;
    const int NWAVES = AGG_BLOCKS * 4;
    for (int i = 0; i < 3; i++) {
        hipLaunchKernelGGL(gemm_sd_kernel, dim3((NN + 31) / 32, 2), dim3(256), 0, stream,
            x_cur, Wsrc + (size_t)i * HD * HD, Wdst + (size_t)i * HD * HD,
            xs_p, (float2*)xd);
        hipLaunchKernelGGL(aggregate_kernel, dim3(AGG_BLOCKS), dim3(256), 0, stream,
            xs_p, (const float2*)xd, efeat_c, meta_c, row_ptr,
            Wedge + (size_t)i * RD * HD, (const float2*)(att + (size_t)i * NH * NC),
            sscale + (size_t)i * NH,
            (const float2*)(ng + (size_t)i * HD), (const float2*)(nb + (size_t)i * HD),
            (float2*)x_cur, (i < 2) ? 1 : 0, NWAVES);
    }
}

// Round 7
// 933.863 us; speedup vs baseline: 1.4463x; 1.1684x over previous
//
#include <hip/hip_runtime.h>
#include <math.h>

#define NN 50000
#define NE 800000
#define IND 256
#define HD 128
#define NH 4
#define NC 32
#define RELN 100
#define RD 16
#define EHD 32

typedef unsigned int uint;
typedef _Float16 half2_t __attribute__((ext_vector_type(2)));

__device__ inline uint pack_bf16(float a, float b) {
    uint ua = __float_as_uint(a), ub = __float_as_uint(b);
    ua += 0x7fffu + ((ua >> 16) & 1u);
    ub += 0x7fffu + ((ub >> 16) & 1u);
    return (ua >> 16) | (ub & 0xffff0000u);
}

__device__ inline uint pack_f16(float a, float b) {
    half2_t h = { (_Float16)a, (_Float16)b };
    return __builtin_bit_cast(uint, h);
}

#if __has_builtin(__builtin_amdgcn_fdot2)
#define FDOT2(a, b, c) __builtin_amdgcn_fdot2((a), (b), (c), false)
#else
static __device__ inline float FDOT2(half2_t a, half2_t b, float c) {
    return c + (float)a.x * (float)b.x + (float)a.y * (float)b.y;
}
#endif

// ---------------- degree count ----------------
__global__ __launch_bounds__(256) void count_kernel(
    const int* __restrict__ dst, int* __restrict__ counts)
{
    int e = blockIdx.x * 256 + threadIdx.x;
    if (e < NE) atomicAdd(&counts[dst[e]], 1);
}

// ---------------- exclusive scan: single block, one ladder ----------------
__global__ __launch_bounds__(1024) void scan_kernel(
    const int* __restrict__ counts, int* __restrict__ row_ptr,
    int* __restrict__ cursor, int n)
{
    __shared__ int wsum[16];
    int tid = threadIdx.x;
    int C = (n + 1023) >> 10;           // 49
    int lo = tid * C, hi = min(lo + C, n);
    int s = 0;
    for (int i = lo; i < hi; i++) s += counts[i];
    int lane = tid & 63;
    int incl = s;
#pragma unroll
    for (int off = 1; off < 64; off <<= 1) {
        int v = __shfl_up(incl, off);
        if (lane >= off) incl += v;
    }
    if (lane == 63) wsum[tid >> 6] = incl;
    __syncthreads();
    if (tid < 16) {
        int v = wsum[tid];
        int inc2 = v;
#pragma unroll
        for (int off = 1; off < 16; off <<= 1) {
            int u = __shfl_up(inc2, off);
            if (tid >= off) inc2 += u;
        }
        wsum[tid] = inc2 - v;           // exclusive wave prefix
    }
    __syncthreads();
    int run = wsum[tid >> 6] + (incl - s);
    for (int i = lo; i < hi; i++) {
        row_ptr[i] = run; cursor[i] = run; run += counts[i];
    }
    if (tid == 1023) row_ptr[n] = run;
}

// ------- edge feature MLPs + CSR placement (fused fill), edge order -------
// efeat written as 8x f16x2 (32 B/edge)
__global__ __launch_bounds__(256) void edge_feat_fill_kernel(
    const float* __restrict__ eattr, const int* __restrict__ src,
    const int* __restrict__ dst, int* __restrict__ cursor,
    const float* __restrict__ dW1, const float* __restrict__ db1,
    const float* __restrict__ dW2, const float* __restrict__ db2,
    const float* __restrict__ cW1, const float* __restrict__ cb1,
    const float* __restrict__ cW2, const float* __restrict__ cb2,
    const float* __restrict__ rel_emb,
    const float* __restrict__ fW1, const float* __restrict__ fb1,
    const float* __restrict__ fg,  const float* __restrict__ fbl,
    const float* __restrict__ fW2, const float* __restrict__ fb2,
    uint4* __restrict__ efeat_h, int2* __restrict__ meta_c)
{
    int e = blockIdx.x * 256 + threadIdx.x;
    if (e >= NE) return;
    float d  = eattr[(size_t)e * 3 + 0];
    float cx = eattr[(size_t)e * 3 + 1];
    int r = (int)eattr[(size_t)e * 3 + 2];
    r = min(max(r, 0), RELN - 1);
    int p = atomicAdd(&cursor[dst[e]], 1);     // CSR slot
    meta_c[p] = make_int2(src[e], __float_as_int(__log2f(d)));

    float df[RD], cf[RD];
#pragma unroll
    for (int k = 0; k < RD; k++) { df[k] = db2[k]; cf[k] = cb2[k]; }
    for (int j = 0; j < EHD; j++) {
        float h1 = fmaxf(d  * dW1[j] + db1[j], 0.f);
        float h2 = fmaxf(cx * cW1[j] + cb1[j], 0.f);
#pragma unroll
        for (int k = 0; k < RD; k++) {
            df[k] += h1 * dW2[j * RD + k];
            cf[k] += h2 * cW2[j * RD + k];
        }
    }
    float hh[2 * RD];
#pragma unroll
    for (int m = 0; m < 2 * RD; m++) hh[m] = fb1[m];
    for (int k = 0; k < RD; k++) {
        float a = df[k], b = cf[k], c = rel_emb[r * RD + k];
#pragma unroll
        for (int m = 0; m < 2 * RD; m++) {
            hh[m] += a * fW1[k * (2 * RD) + m]
                   + b * fW1[(RD + k) * (2 * RD) + m]
                   + c * fW1[(2 * RD + k) * (2 * RD) + m];
        }
    }
    float s = 0.f;
#pragma unroll
    for (int m = 0; m < 2 * RD; m++) s += hh[m];
    float mean = s * (1.f / (2 * RD));
    float s2 = 0.f;
#pragma unroll
    for (int m = 0; m < 2 * RD; m++) { float dd = hh[m] - mean; s2 += dd * dd; }
    float rs = rsqrtf(s2 * (1.f / (2 * RD)) + 1e-5f);
#pragma unroll
    for (int m = 0; m < 2 * RD; m++)
        hh[m] = fmaxf((hh[m] - mean) * rs * fg[m] + fbl[m], 0.f);

    float ef[RD];
#pragma unroll
    for (int k = 0; k < RD; k++) ef[k] = fb2[k];
    for (int m = 0; m < 2 * RD; m++) {
        float hv = hh[m];
#pragma unroll
        for (int k = 0; k < RD; k++) ef[k] += hv * fW2[m * RD + k];
    }
    uint4 e0, e1;
    e0.x = pack_f16(ef[0],  ef[1]);  e0.y = pack_f16(ef[2],  ef[3]);
    e0.z = pack_f16(ef[4],  ef[5]);  e0.w = pack_f16(ef[6],  ef[7]);
    e1.x = pack_f16(ef[8],  ef[9]);  e1.y = pack_f16(ef[10], ef[11]);
    e1.z = pack_f16(ef[12], ef[13]); e1.w = pack_f16(ef[14], ef[15]);
    efeat_h[(size_t)p * 2 + 0] = e0;
    efeat_h[(size_t)p * 2 + 1] = e1;
}

// ---------------- input LN + projection (8 nodes / block) ----------------
__global__ __launch_bounds__(256) void ln_proj_kernel(
    const float* __restrict__ x, const float* __restrict__ g, const float* __restrict__ b,
    const float* __restrict__ W, const float* __restrict__ pb, float* __restrict__ x0)
{
    __shared__ float xr[8][IND];
    __shared__ float mv[8][2];
    int nb = blockIdx.x * 8;
    int tid = threadIdx.x;
    const float4* xv = (const float4*)(x + (size_t)nb * IND);
    float4* xl = (float4*)&xr[0][0];
    xl[tid] = xv[tid];
    xl[tid + 256] = xv[tid + 256];
    __syncthreads();
    int node = tid >> 5, lane = tid & 31;
    float s1 = 0.f, s2 = 0.f;
#pragma unroll
    for (int j = 0; j < 8; j++) { float v = xr[node][lane + 32 * j]; s1 += v; s2 += v * v; }
#pragma unroll
    for (int off = 16; off >= 1; off >>= 1) { s1 += __shfl_xor(s1, off); s2 += __shfl_xor(s2, off); }
    if (lane == 0) {
        float mean = s1 * (1.f / IND);
        mv[node][0] = mean;
        mv[node][1] = rsqrtf(s2 * (1.f / IND) - mean * mean + 1e-5f);
    }
    __syncthreads();
#pragma unroll
    for (int j = 0; j < 8; j++) {
        int k = lane + 32 * j;
        xr[node][k] = (xr[node][k] - mv[node][0]) * mv[node][1] * g[k] + b[k];
    }
    __syncthreads();
    int col = tid & 127, r0 = (tid >> 7) * 4;
    float acc[4] = {0.f, 0.f, 0.f, 0.f};
    for (int k = 0; k < IND; k += 4) {
        float4 x4[4];
#pragma unroll
        for (int r = 0; r < 4; r++) x4[r] = *(const float4*)&xr[r0 + r][k];
        float w0 = W[(k + 0) * HD + col];
        float w1 = W[(k + 1) * HD + col];
        float w2 = W[(k + 2) * HD + col];
        float w3 = W[(k + 3) * HD + col];
#pragma unroll
        for (int r = 0; r < 4; r++)
            acc[r] += x4[r].x * w0 + x4[r].y * w1 + x4[r].z * w2 + x4[r].w * w3;
    }
    float pbv = pb[col];
#pragma unroll
    for (int r = 0; r < 4; r++)
        x0[(size_t)(nb + r0 + r) * HD + col] = acc[r] + pbv;
}

// ------- xs = bf16-packed x@Wsrc ; xd = f32 x@Wdst (one block, both) -------
__global__ __launch_bounds__(256) void gemm_sd_kernel(
    const float* __restrict__ x, const float* __restrict__ Ws, const float* __restrict__ Wd,
    uint* __restrict__ xs_p, float2* __restrict__ xd2)
{
    __shared__ float xt[32][HD];
    int nb = blockIdx.x * 32;
    int tid = threadIdx.x;
    const float4* xv = (const float4*)(x + (size_t)nb * HD);
    float4* xl = (float4*)&xt[0][0];
    int validf4 = (NN - nb >= 32) ? 1024 : (NN - nb) * 32;
    for (int idx = tid; idx < 1024; idx += 256) {
        float4 v = {0.f, 0.f, 0.f, 0.f};
        if (idx < validf4) v = xv[idx];
        xl[idx] = v;
    }
    __syncthreads();
    int cp = tid & 63;                   // column pair: cols 2cp, 2cp+1
    int r0 = (tid >> 6) * 8;
#pragma unroll
    for (int ct = 0; ct < 2; ct++) {
        const float2* W2v = (const float2*)(ct ? Wd : Ws);
        float a0[8] = {0.f}, a1[8] = {0.f};
        for (int k = 0; k < HD; k += 4) {
            float4 x4[8];
#pragma unroll
            for (int r = 0; r < 8; r++) x4[r] = *(const float4*)&xt[r0 + r][k];
            float2 w0 = W2v[(k + 0) * 64 + cp];
            float2 w1 = W2v[(k + 1) * 64 + cp];
            float2 w2 = W2v[(k + 2) * 64 + cp];
            float2 w3 = W2v[(k + 3) * 64 + cp];
#pragma unroll
            for (int r = 0; r < 8; r++) {
                a0[r] += x4[r].x * w0.x + x4[r].y * w1.x + x4[r].z * w2.x + x4[r].w * w3.x;
                a1[r] += x4[r].x * w0.y + x4[r].y * w1.y + x4[r].z * w2.y + x4[r].w * w3.y;
            }
        }
        if (ct == 0) {
#pragma unroll
            for (int r = 0; r < 8; r++) {
                int n = nb + r0 + r;
                if (n < NN) xs_p[(size_t)n * 64 + cp] = pack_bf16(a0[r], a1[r]);
            }
        } else {
#pragma unroll
            for (int r = 0; r < 8; r++) {
                int n = nb + r0 + r;
                if (n < NN) xd2[(size_t)n * 64 + cp] = make_float2(a0[r], a1[r]);
            }
        }
    }
}

// ------- per-layer attention aggregate + LN + ELU + residual -------
// wave = worker, grid-stride over nodes; software-pipelined 4-edge batches;
// f16 efeat + fdot2
__global__ __launch_bounds__(256) void aggregate_kernel(
    const uint* __restrict__ xs_p, const float2* __restrict__ xd2,
    const uint4* __restrict__ efeat_h, const int2* __restrict__ meta_c,
    const int* __restrict__ row_ptr,
    const float* __restrict__ Wedge_i, const float2* __restrict__ att2,
    const float* __restrict__ sscale_i, const float2* __restrict__ ng2,
    const float2* __restrict__ nb2, float2* __restrict__ xio2,
    int apply_dist, int nwaves)
{
    int l = threadIdx.x & 63;
    int wid = blockIdx.x * 4 + __builtin_amdgcn_readfirstlane(threadIdx.x >> 6);

    // -------- layer constants: loaded ONCE per wave --------
    int c0 = 2 * l, c1 = 2 * l + 1;
    half2_t wxh[8], wyh[8];
#pragma unroll
    for (int q = 0; q < 8; q++) {
        wxh[q] = (half2_t){ (_Float16)Wedge_i[(2 * q) * HD + c0],
                            (_Float16)Wedge_i[(2 * q + 1) * HD + c0] };
        wyh[q] = (half2_t){ (_Float16)Wedge_i[(2 * q) * HD + c1],
                            (_Float16)Wedge_i[(2 * q + 1) * HD + c1] };
    }
    float2 attv = att2[l];
    float sc = sscale_i[l >> 4];
    float2 g = ng2[l], bb = nb2[l];

    for (int node = wid; node < NN; node += nwaves) {
        int e0 = row_ptr[node], e1 = row_ptr[node + 1];
        float2 xdv  = xd2[(size_t)node * 64 + l];
        float2 xres = xio2[(size_t)node * 64 + l];
        float esum = 0.f;
        float2 macc = {0.f, 0.f};

        if (e0 < e1) {
            int2 mt[4]; uint xw[4]; uint4 ef[4][2];
            // prologue: batch 0 loads
#pragma unroll
            for (int j = 0; j < 4; j++) {
                int pp = min(e0 + j, e1 - 1);
                mt[j] = meta_c[pp];
                ef[j][0] = efeat_h[(size_t)pp * 2 + 0];
                ef[j][1] = efeat_h[(size_t)pp * 2 + 1];
            }
#pragma unroll
            for (int j = 0; j < 4; j++) xw[j] = xs_p[(size_t)mt[j].x * 64 + l];

#pragma unroll 2
            for (int b = e0; b < e1; b += 4) {
                int bn = b + 4;
                bool more = bn < e1;
                int2 mtn[4]; uint xwn[4]; uint4 efn[4][2];
                if (more) {
                    // prefetch next batch: meta + efeat + gathers all in flight
#pragma unroll
                    for (int j = 0; j < 4; j++) {
                        int pp = min(bn + j, e1 - 1);
                        mtn[j] = meta_c[pp];
                        efn[j][0] = efeat_h[(size_t)pp * 2 + 0];
                        efn[j][1] = efeat_h[(size_t)pp * 2 + 1];
                    }
#pragma unroll
                    for (int j = 0; j < 4; j++) xwn[j] = xs_p[(size_t)mtn[j].x * 64 + l];
                }
                // compute current batch from registers
#pragma unroll
                for (int j = 0; j < 4; j++) {
                    const half2_t* eh = (const half2_t*)&ef[j][0];
                    float efx = 0.f, efy = 0.f;
#pragma unroll
                    for (int q = 0; q < 8; q++) {
                        efx = FDOT2(eh[q], wxh[q], efx);
                        efy = FDOT2(eh[q], wyh[q], efy);
                    }
                    float xvx = __uint_as_float(xw[j] << 16);
                    float xvy = __uint_as_float(xw[j] & 0xffff0000u);
                    float zx = xvx + xdv.x + efx;
                    float zy = xvy + xdv.y + efy;
                    float tx = 1.f - 2.f * __builtin_amdgcn_rcpf(__expf(2.f * zx) + 1.f);
                    float ty = 1.f - 2.f * __builtin_amdgcn_rcpf(__expf(2.f * zy) + 1.f);
                    float a = tx * attv.x + ty * attv.y;
#pragma unroll
                    for (int off = 8; off >= 1; off >>= 1) a += __shfl_xor(a, off);
                    if (apply_dist) a *= exp2f(__int_as_float(mt[j].y) * sc);
                    float ea = __expf(a);
                    ea = (b + j < e1) ? ea : 0.f;
                    esum += ea;
                    macc.x += xvx * ea;
                    macc.y += xvy * ea;
                }
                if (more) {
#pragma unroll
                    for (int j = 0; j < 4; j++) {
                        mt[j] = mtn[j]; xw[j] = xwn[j];
                        ef[j][0] = efn[j][0]; ef[j][1] = efn[j][1];
                    }
                }
            }
        }
        float inv = __builtin_amdgcn_rcpf(esum + 1e-8f);
        float2 outv = { macc.x * inv, macc.y * inv };

        float s1 = outv.x + outv.y;
        float s2 = outv.x * outv.x + outv.y * outv.y;
#pragma unroll
        for (int off = 32; off >= 1; off >>= 1) { s1 += __shfl_xor(s1, off); s2 += __shfl_xor(s2, off); }
        float mean = s1 * (1.f / HD);
        float var = s2 * (1.f / HD) - mean * mean;
        float rstd = rsqrtf(var + 1e-5f);
        float yx = (outv.x - mean) * rstd * g.x + bb.x;
        float yy = (outv.y - mean) * rstd * g.y + bb.y;
        float ex = (yx > 0.f) ? yx : expm1f(yx);
        float ey = (yy > 0.f) ? yy : expm1f(yy);
        float2 res;
        res.x = ex + xres.x;
        res.y = ey + xres.y;
        xio2[(size_t)node * 64 + l] = res;
    }
}

extern "C" void kernel_launch(void* const* d_in, const int* in_sizes, int n_in,
                              void* d_out, int out_size, void* d_ws, size_t ws_size,
                              hipStream_t stream)
{
    const float* x_in   = (const float*)d_in[0];
    const int*   eidx   = (const int*)  d_in[1];
    const float* eattr  = (const float*)d_in[2];
    const float* in_g   = (const float*)d_in[3];
    const float* in_b   = (const float*)d_in[4];
    const float* proj_W = (const float*)d_in[5];
    const float* proj_b = (const float*)d_in[6];
    const float* dW1    = (const float*)d_in[7];
    const float* db1    = (const float*)d_in[8];
    const float* dW2    = (const float*)d_in[9];
    const float* db2    = (const float*)d_in[10];
    const float* cW1    = (const float*)d_in[11];
    const float* cb1    = (const float*)d_in[12];
    const float* cW2    = (const float*)d_in[13];
    const float* cb2    = (const float*)d_in[14];
    const float* rel_emb= (const float*)d_in[15];
    const float* fW1    = (const float*)d_in[16];
    const float* fb1    = (const float*)d_in[17];
    const float* fg     = (const float*)d_in[18];
    const float* fbl    = (const float*)d_in[19];
    const float* fW2    = (const float*)d_in[20];
    const float* fb2    = (const float*)d_in[21];
    const float* Wsrc   = (const float*)d_in[22];
    const float* Wdst   = (const float*)d_in[23];
    const float* Wedge  = (const float*)d_in[24];
    const float* att    = (const float*)d_in[25];
    const float* sscale = (const float*)d_in[26];
    const float* ng     = (const float*)d_in[27];
    const float* nb     = (const float*)d_in[28];

    const int* src = eidx;
    const int* dst = eidx + NE;

    char* p = (char*)d_ws;
    auto alloc = [&](size_t bytes) -> void* {
        void* r = p;
        p += (bytes + 255) & ~(size_t)255;
        return r;
    };
    uint*  xs_p    = (uint*) alloc((size_t)NN * 64 * 4);      // bf16-packed
    float* xd      = (float*)alloc((size_t)NN * HD * 4);
    uint4* efeat_h = (uint4*)alloc((size_t)NE * 32);          // f16-packed
    int*   counts  = (int*)  alloc((size_t)NN * 4);
    int*   row_ptr = (int*)  alloc(((size_t)NN + 1) * 4);
    int*   cursor  = (int*)  alloc((size_t)NN * 4);
    int2*  meta_c  = (int2*) alloc((size_t)NE * 8);

    float* x_cur = (float*)d_out;

    hipMemsetAsync(counts, 0, (size_t)NN * 4, stream);
    hipLaunchKernelGGL(count_kernel, dim3(NE / 256), dim3(256), 0, stream, dst, counts);
    hipLaunchKernelGGL(scan_kernel, dim3(1), dim3(1024), 0, stream,
        counts, row_ptr, cursor, NN);
    hipLaunchKernelGGL(edge_feat_fill_kernel, dim3(NE / 256), dim3(256), 0, stream,
        eattr, src, dst, cursor, dW1, db1, dW2, db2, cW1, cb1, cW2, cb2, rel_emb,
        fW1, fb1, fg, fbl, fW2, fb2, efeat_h, meta_c);
    hipLaunchKernelGGL(ln_proj_kernel, dim3(NN / 8), dim3(256), 0, stream,
        x_in, in_g, in_b, proj_W, proj_b, x_cur);

    const int AGG_BLOCKS = 2048;
    const int NWAVES = AGG_BLOCKS * 4;
    for (int i = 0; i < 3; i++) {
        hipLaunchKernelGGL(gemm_sd_kernel, dim3((NN + 31) / 32), dim3(256), 0, stream,
            x_cur, Wsrc + (size_t)i * HD * HD, Wdst + (size_t)i * HD * HD,
            xs_p, (float2*)xd);
        hipLaunchKernelGGL(aggregate_kernel, dim3(AGG_BLOCKS), dim3(256), 0, stream,
            xs_p, (const float2*)xd, efeat_h, meta_c, row_ptr,
            Wedge + (size_t)i * RD * HD, (const float2*)(att + (size_t)i * NH * NC),
            sscale + (size_t)i * NH,
            (const float2*)(ng + (size_t)i * HD), (const float2*)(nb + (size_t)i * HD),
            (float2*)x_cur, (i < 2) ? 1 : 0, NWAVES);
    }
}